// Round 15
// baseline (104.937 us; speedup 1.0000x reference)
//
#include <hip/hip_runtime.h>
#include <hip/hip_bf16.h>

typedef __attribute__((ext_vector_type(8))) int   i32x8;   // 32 B = fp8 MFMA A/B operand (8 VGPRs)
typedef __attribute__((ext_vector_type(4))) int   i32x4;
typedef __attribute__((ext_vector_type(4))) float f32x4;   // MFMA C/D

constexpr int BB = 4096;   // batch B
constexpr int D  = 256;    // feature dim
constexpr int R2 = 8192;   // 2B rows of z
constexpr int TB = 256;    // tile edge (rows and cols per block)
constexpr int NG = TB / 16;             // 16 n-groups of 16 cols per wave
// z pre-scaled by sqrt(2*log2(e)): dot = log2(e)*sim/TEMP -> exp2(dot) = exp(sim/TEMP).
constexpr float SCALE = 1.6986436005760381f;
constexpr float E2 = 7.38905609893065f;  // exp(2) == exp(diag sim)

// Async 16B/lane global->LDS DMA. LDS dest is wave-uniform base + lane*16 (HW).
__device__ __forceinline__ void async16(const unsigned char* g, unsigned char* l) {
    __builtin_amdgcn_global_load_lds(
        (const __attribute__((address_space(1))) void*)g,
        (__attribute__((address_space(3))) void*)l,
        16, 0, 0);
}

// Unit-scale (E8M0 127 = 2^0) MX-fp8 MFMA, fmt A/B = fp8-e4m3. Verified correct R5-R14.
#define MFMA8(A, B, C) \
    __builtin_amdgcn_mfma_scale_f32_16x16x128_f8f6f4((A), (B), (C), 0, 0, 0, 127, 0, 127)

// Kernel A: L2-normalize rows, scale by sqrt(2*log2e), store fp8-e4m3 z[8192][256];
// pos[k] = 2*cos(xi_k, xj_k). Blocks 0-31 also zero S[8192]; block 0 zeros out[0].
__global__ __launch_bounds__(256) void norm_kernel(const float* __restrict__ xi,
                                                   const float* __restrict__ xj,
                                                   int* __restrict__ z8,
                                                   float* __restrict__ pos,
                                                   float* __restrict__ S,
                                                   float* __restrict__ out) {
    const int wid = threadIdx.x >> 6, lane = threadIdx.x & 63;
    const int k = blockIdx.x * 4 + wid;
    if (blockIdx.x == 0 && threadIdx.x == 0) out[0] = 0.f;
    if (blockIdx.x < 32) S[blockIdx.x * 256 + threadIdx.x] = 0.f;
    const float4* a4 = reinterpret_cast<const float4*>(xi + (size_t)k * D);
    const float4* b4 = reinterpret_cast<const float4*>(xj + (size_t)k * D);
    float4 a = a4[lane], b = b4[lane];
    float ssi = a.x*a.x + a.y*a.y + a.z*a.z + a.w*a.w;
    float ssj = b.x*b.x + b.y*b.y + b.z*b.z + b.w*b.w;
    float dot = a.x*b.x + a.y*b.y + a.z*b.z + a.w*b.w;
#pragma unroll
    for (int off = 32; off; off >>= 1) {
        ssi += __shfl_xor(ssi, off);
        ssj += __shfl_xor(ssj, off);
        dot += __shfl_xor(dot, off);
    }
    const float inv_i = 1.0f / fmaxf(sqrtf(ssi), 1e-12f);
    const float inv_j = 1.0f / fmaxf(sqrtf(ssj), 1e-12f);
    const float si = inv_i * SCALE, sj = inv_j * SCALE;
    int pi = __builtin_amdgcn_cvt_pk_fp8_f32(a.x*si, a.y*si, 0, false);
    pi     = __builtin_amdgcn_cvt_pk_fp8_f32(a.z*si, a.w*si, pi, true);
    int pj = __builtin_amdgcn_cvt_pk_fp8_f32(b.x*sj, b.y*sj, 0, false);
    pj     = __builtin_amdgcn_cvt_pk_fp8_f32(b.z*sj, b.w*sj, pj, true);
    z8[(size_t)k * 64 + lane]        = pi;
    z8[(size_t)(k + BB) * 64 + lane] = pj;
    if (lane == 0) pos[k] = dot * inv_i * inv_j * 2.0f;
}

// Kernel B (triangular): for tile-pair (I,J), J>=I, compute the 256x256 tile
// exp(z_I . z_J^T) ONCE and scatter BOTH row-sums (-> S[rows of I]) and, for J>I,
// col-sums (-> S[rows of J], valid by symmetry). 528 of 1024 tiles -> work halves
// regardless of which structural effect causes the ~30us plateau (R8/R11/R14 all
// geometry variants tied). Skeleton = R14's proven-clean design: 256 thr, m=4
// (4 waves x 64 rows), whole 256-col J-tile staged once into 64 KB LDS (hard
// LDS-cap at 2 blocks/CU kills the allocator spill-for-occupancy pathology seen
// in R5-R13), ONE barrier, pure ds_read+MFMA+exp loop. S updated via fp32
// device atomics (~400k adds, trivial for L2).
// fp8 layouts + unit scales + DMA/read swizzles verified R5-R14; A-frag pin (R9/R10).
__global__ __launch_bounds__(256) void sim_kernel(const unsigned char* __restrict__ z8,
                                                  float* __restrict__ S) {
    const int bi = blockIdx.x, bj = blockIdx.y;
    if (bj < bi) return;                       // uniform: whole block exits
    __shared__ unsigned char tb[TB * D];       // 64 KB -> LDS-capped 2 blocks/CU
    const int tid = threadIdx.x;
    const int wid = tid >> 6, lane = tid & 63;
    const int lrow = lane & 15, quad = lane >> 4;
    const int r0 = bi * TB + wid * 64;         // this wave's 64 rows
    const int cbase = bj * TB;                 // this block's 256 cols
    const bool offdiag = (bj != bi);

    // Staging (verified): round i stages rows i*16 + (tid>>4); physical granule
    // p = tid&15 (forced dest tb + i*4096 + tid*16) <- logical p ^ (row&15).
    {
        const int srow16 = tid >> 4;
        const int srcg   = (tid & 15) ^ srow16;
        const unsigned char* gs = z8 + (size_t)(cbase + srow16) * D + srcg * 16;
        unsigned char* ds = tb + tid * 16;
#pragma unroll
        for (int i = 0; i < 16; ++i)
            async16(gs + (size_t)i * 16 * D, ds + i * 4096);
    }

    // A fragments: 64 rows x K=256 (row = lane&15, k = quad*32 + linear; half1 +128).
    const unsigned char* abase = z8 + (size_t)(r0 + lrow) * D + quad * 32;
    i32x8 a0k0 = *reinterpret_cast<const i32x8*>(abase             );
    i32x8 a0k1 = *reinterpret_cast<const i32x8*>(abase        + 128);
    i32x8 a1k0 = *reinterpret_cast<const i32x8*>(abase + 16*D      );
    i32x8 a1k1 = *reinterpret_cast<const i32x8*>(abase + 16*D + 128);
    i32x8 a2k0 = *reinterpret_cast<const i32x8*>(abase + 32*D      );
    i32x8 a2k1 = *reinterpret_cast<const i32x8*>(abase + 32*D + 128);
    i32x8 a3k0 = *reinterpret_cast<const i32x8*>(abase + 48*D      );
    i32x8 a3k1 = *reinterpret_cast<const i32x8*>(abase + 48*D + 128);
    asm volatile("" : "+v"(a0k0), "+v"(a0k1), "+v"(a1k0), "+v"(a1k1),
                      "+v"(a2k0), "+v"(a2k1), "+v"(a3k0), "+v"(a3k1));

    f32x4 racc0 = {0.f,0.f,0.f,0.f}, racc1 = {0.f,0.f,0.f,0.f};
    f32x4 racc2 = {0.f,0.f,0.f,0.f}, racc3 = {0.f,0.f,0.f,0.f};
    float cacc[NG];   // per-lane col-sum slices (constant-indexed, fully unrolled)
#pragma unroll
    for (int n = 0; n < NG; ++n) cacc[n] = 0.f;

    __syncthreads();   // the ONLY barrier: staging DMA drained

    // Read swizzle (verified): col row = n*16+lrow, physical granule = logical^lrow.
    const int pe0 = (quad * 2) ^ lrow;
    const int pe1 = (8 + quad * 2) ^ lrow;
    const unsigned char* rbp = tb + lrow * D;
#pragma unroll
    for (int n = 0; n < NG; ++n) {
        const i32x4 lo0 = *reinterpret_cast<const i32x4*>(rbp + pe0*16);
        const i32x4 hi0 = *reinterpret_cast<const i32x4*>(rbp + (pe0^1)*16);
        const i32x4 lo1 = *reinterpret_cast<const i32x4*>(rbp + pe1*16);
        const i32x4 hi1 = *reinterpret_cast<const i32x4*>(rbp + (pe1^1)*16);
        rbp += 16 * D;
        const i32x8 b0 = __builtin_shufflevector(lo0, hi0, 0,1,2,3,4,5,6,7);
        const i32x8 b1 = __builtin_shufflevector(lo1, hi1, 0,1,2,3,4,5,6,7);

        f32x4 c0 = {0.f,0.f,0.f,0.f}, c1 = {0.f,0.f,0.f,0.f};
        f32x4 c2 = {0.f,0.f,0.f,0.f}, c3 = {0.f,0.f,0.f,0.f};
        c0 = MFMA8(a0k0, b0, c0);  c0 = MFMA8(a0k1, b1, c0);
        c1 = MFMA8(a1k0, b0, c1);  c1 = MFMA8(a1k1, b1, c1);
        c2 = MFMA8(a2k0, b0, c2);  c2 = MFMA8(a2k1, b1, c2);
        c3 = MFMA8(a3k0, b0, c3);  c3 = MFMA8(a3k1, b1, c3);

        const float e00=__builtin_amdgcn_exp2f(c0[0]), e01=__builtin_amdgcn_exp2f(c0[1]);
        const float e02=__builtin_amdgcn_exp2f(c0[2]), e03=__builtin_amdgcn_exp2f(c0[3]);
        const float e10=__builtin_amdgcn_exp2f(c1[0]), e11=__builtin_amdgcn_exp2f(c1[1]);
        const float e12=__builtin_amdgcn_exp2f(c1[2]), e13=__builtin_amdgcn_exp2f(c1[3]);
        const float e20=__builtin_amdgcn_exp2f(c2[0]), e21=__builtin_amdgcn_exp2f(c2[1]);
        const float e22=__builtin_amdgcn_exp2f(c2[2]), e23=__builtin_amdgcn_exp2f(c2[3]);
        const float e30=__builtin_amdgcn_exp2f(c3[0]), e31=__builtin_amdgcn_exp2f(c3[1]);
        const float e32=__builtin_amdgcn_exp2f(c3[2]), e33=__builtin_amdgcn_exp2f(c3[3]);

        racc0[0]+=e00; racc0[1]+=e01; racc0[2]+=e02; racc0[3]+=e03;
        racc1[0]+=e10; racc1[1]+=e11; racc1[2]+=e12; racc1[3]+=e13;
        racc2[0]+=e20; racc2[1]+=e21; racc2[2]+=e22; racc2[3]+=e23;
        racc3[0]+=e30; racc3[1]+=e31; racc3[2]+=e32; racc3[3]+=e33;

        // Col-sum slice: sum this lane's 16 exps (rows quad*4+j, m=0..3), then
        // reduce over quads -> full 64-row column sum for col n*16+lrow.
        float cp = ((e00+e01)+(e02+e03)) + ((e10+e11)+(e12+e13))
                 + ((e20+e21)+(e22+e23)) + ((e30+e31)+(e32+e33));
        cp += __shfl_xor(cp, 16);
        cp += __shfl_xor(cp, 32);
        cacc[n] = cp;
    }

    // Row sums -> S[rows of I]: reduce over lrow (col) bits.
#define REDUCE_ATOMIC(RV, M)                                                    \
    {                                                                           \
        _Pragma("unroll")                                                       \
        for (int j = 0; j < 4; ++j) {                                           \
            float v = (RV)[j];                                                  \
            v += __shfl_xor(v, 1);                                              \
            v += __shfl_xor(v, 2);                                              \
            v += __shfl_xor(v, 4);                                              \
            v += __shfl_xor(v, 8);                                              \
            if (lrow == 0) atomicAdd(&S[r0 + (M)*16 + quad*4 + j], v);          \
        }                                                                       \
    }
    REDUCE_ATOMIC(racc0, 0)
    REDUCE_ATOMIC(racc1, 1)
    REDUCE_ATOMIC(racc2, 2)
    REDUCE_ATOMIC(racc3, 3)
#undef REDUCE_ATOMIC

    // Col sums -> S[rows of J] (symmetry), off-diagonal tiles only.
    if (offdiag) {
#pragma unroll
        for (int n = 0; n < NG; ++n)
            if (quad == 0) atomicAdd(&S[cbase + n*16 + lrow], cacc[n]);
    }
}

// Kernel C: loss_r = log(exp(p_r) + S_r - e^2) - p_r ; atomicAdd(out, blocksum/R2).
// 32 blocks x 256 threads; out zero-initialized by norm_kernel.
__global__ __launch_bounds__(256) void reduce_kernel(const float* __restrict__ S,
                                                     const float* __restrict__ pos,
                                                     float* __restrict__ out) {
    __shared__ float wsum[4];
    const int tid = threadIdx.x;
    const int r = blockIdx.x * 256 + tid;
    const float p = pos[r & (BB - 1)];
    float lsum = __logf(__expf(p) + S[r] - E2) - p;
#pragma unroll
    for (int off = 32; off; off >>= 1) lsum += __shfl_xor(lsum, off);
    if ((tid & 63) == 0) wsum[tid >> 6] = lsum;
    __syncthreads();
    if (tid == 0) {
        float t = wsum[0] + wsum[1] + wsum[2] + wsum[3];
        atomicAdd(out, t * (1.0f / (float)R2));
    }
}

extern "C" void kernel_launch(void* const* d_in, const int* in_sizes, int n_in,
                              void* d_out, int out_size, void* d_ws, size_t ws_size,
                              hipStream_t stream) {
    (void)in_sizes; (void)n_in; (void)out_size; (void)ws_size;
    const float* xi = (const float*)d_in[0];
    const float* xj = (const float*)d_in[1];
    float* out = (float*)d_out;

    unsigned char* z8 = (unsigned char*)d_ws;                                  // 8192*256 = 2 MB
    float* S   = (float*)((char*)d_ws + (size_t)R2 * D);                       // 8192*4 = 32 KB
    float* pos = (float*)((char*)d_ws + (size_t)R2 * D + R2 * 4);              // 16 KB

    norm_kernel<<<BB / 4, 256, 0, stream>>>(xi, xj, (int*)z8, pos, S, out);
    sim_kernel<<<dim3(R2 / TB, R2 / TB), 256, 0, stream>>>(z8, S);
    reduce_kernel<<<R2 / 256, 256, 0, stream>>>(S, pos, out);
}